// Round 1
// baseline (977.692 us; speedup 1.0000x reference)
//
#include <hip/hip_runtime.h>
#include <math.h>

// Problem constants (fixed by reference): B*S = 262144 rows
#define DQ 14      // query dim
#define HD 32      // hidden dim
#define DK 8       // projected dim
#define NK 240     // number of E8 root keys
#define DV 256     // value dim
#define RB 32      // rows per block
#define KC 16      // k-chunk for content staging (240 = 15 * 16, exact)

// Fused: projection -> GELU -> projection -> L2norm -> sim -> softmax -> attn@values
// Block = 256 threads (4 waves), handles RB=32 rows.
__global__ __launch_bounds__(256, 2)
void em_fused(const float* __restrict__ query,
              const float* __restrict__ W1, const float* __restrict__ b1,
              const float* __restrict__ W2, const float* __restrict__ b2,
              const float* __restrict__ values, const float* __restrict__ keys,
              float* __restrict__ out_content, float* __restrict__ out_attn)
{
    __shared__ float s_x[RB][DQ];        // 1792 B
    __shared__ float s_h[RB][HD + 1];    // 4224 B (pad: break 8-way bank conflict in q8 phase)
    __shared__ float s_q8[RB][DK + 1];   // 1152 B
    __shared__ float s_attnT[NK][36];    // 34560 B (stride 36: float4-aligned rows + bank spread)
    __shared__ float s_v[KC][DV];        // 16384 B
    // total ~58.1 KB -> 2 blocks/CU

    const int tid = threadIdx.x;
    const int row0 = blockIdx.x * RB;

    // ---- stage x tile: rows contiguous, 448 floats, coalesced ----
    for (int e = tid; e < RB * DQ; e += 256) {
        s_x[e / DQ][e % DQ] = query[(long)row0 * DQ + e];
    }
    __syncthreads();

    // ---- h = gelu(x @ W1^T + b1): 32 rows x 32 outs = 1024 tasks ----
    #pragma unroll
    for (int it = 0; it < 4; ++it) {
        int task = it * 256 + tid;
        int r = task >> 5, j = task & 31;
        float acc = b1[j];
        #pragma unroll
        for (int c = 0; c < DQ; ++c) acc += s_x[r][c] * W1[j * DQ + c];
        // exact GELU: x * 0.5 * (1 + erf(x/sqrt(2)))
        s_h[r][j] = 0.5f * acc * (1.0f + erff(acc * 0.70710678118654752f));
    }
    __syncthreads();

    // ---- q8 = h @ W2^T + b2: 32 rows x 8 = 256 tasks ----
    {
        int r = tid >> 3, i = tid & 7;
        float acc = b2[i];
        #pragma unroll
        for (int c = 0; c < HD; ++c) acc += s_h[r][c] * W2[i * HD + c];
        s_q8[r][i] = acc;
    }
    __syncthreads();

    // ---- L2 normalize q8 (one thread per row) ----
    if (tid < RB) {
        float ss = 0.f;
        #pragma unroll
        for (int i = 0; i < DK; ++i) { float v = s_q8[tid][i]; ss += v * v; }
        float inv = 1.0f / fmaxf(sqrtf(ss), 1e-12f);
        #pragma unroll
        for (int i = 0; i < DK; ++i) s_q8[tid][i] *= inv;
    }
    __syncthreads();

    // ---- sim + softmax: one wave handles 8 rows; lane covers t = lane + 64*s ----
    {
        const int wave = tid >> 6, lane = tid & 63;
        for (int rr = 0; rr < 8; ++rr) {
            int r = wave * 8 + rr;
            float q[DK];
            #pragma unroll
            for (int c = 0; c < DK; ++c) q[c] = s_q8[r][c];
            float ex[4];
            float ssum = 0.f;
            #pragma unroll
            for (int s = 0; s < 4; ++s) {
                int t = lane + 64 * s;
                float v = 0.f;
                if (t < NK) {
                    float sim = 0.f;
                    #pragma unroll
                    for (int c = 0; c < DK; ++c) sim += q[c] * keys[t * DK + c];
                    v = __expf(2.0f * sim);  // BETA = 2.0; scores in [-2,2], no max-sub needed
                }
                ex[s] = v;
                ssum += v;
            }
            #pragma unroll
            for (int m = 1; m < 64; m <<= 1) ssum += __shfl_xor(ssum, m, 64);
            float inv = 1.0f / ssum;
            #pragma unroll
            for (int s = 0; s < 4; ++s) {
                int t = lane + 64 * s;
                if (t < NK) {
                    float a = ex[s] * inv;
                    s_attnT[t][r] = a;                          // transposed for content phase
                    out_attn[(long)(row0 + r) * NK + t] = a;    // coalesced global write
                }
            }
        }
    }
    __syncthreads();

    // ---- content = attn @ values: thread tile = 8 rows x 4 cols ----
    const int rg = tid >> 6;   // wave id -> rows rg*8 .. rg*8+7
    const int cg = tid & 63;   // cols cg*4 .. cg*4+3
    float acc[8][4];
    #pragma unroll
    for (int a = 0; a < 8; ++a)
        #pragma unroll
        for (int b = 0; b < 4; ++b) acc[a][b] = 0.f;

    for (int kc = 0; kc < NK; kc += KC) {
        // stage values chunk: KC x 256, coalesced
        #pragma unroll
        for (int i = 0; i < KC; ++i) {
            s_v[i][tid] = values[(long)(kc + i) * DV + tid];
        }
        __syncthreads();
        #pragma unroll
        for (int j = 0; j < KC; ++j) {
            float4 v  = *(const float4*)&s_v[j][cg * 4];
            float4 aA = *(const float4*)&s_attnT[kc + j][rg * 8];      // rows 0..3 (broadcast)
            float4 aB = *(const float4*)&s_attnT[kc + j][rg * 8 + 4];  // rows 4..7 (broadcast)
            acc[0][0] += aA.x * v.x; acc[0][1] += aA.x * v.y; acc[0][2] += aA.x * v.z; acc[0][3] += aA.x * v.w;
            acc[1][0] += aA.y * v.x; acc[1][1] += aA.y * v.y; acc[1][2] += aA.y * v.z; acc[1][3] += aA.y * v.w;
            acc[2][0] += aA.z * v.x; acc[2][1] += aA.z * v.y; acc[2][2] += aA.z * v.z; acc[2][3] += aA.z * v.w;
            acc[3][0] += aA.w * v.x; acc[3][1] += aA.w * v.y; acc[3][2] += aA.w * v.z; acc[3][3] += aA.w * v.w;
            acc[4][0] += aB.x * v.x; acc[4][1] += aB.x * v.y; acc[4][2] += aB.x * v.z; acc[4][3] += aB.x * v.w;
            acc[5][0] += aB.y * v.x; acc[5][1] += aB.y * v.y; acc[5][2] += aB.y * v.z; acc[5][3] += aB.y * v.w;
            acc[6][0] += aB.z * v.x; acc[6][1] += aB.z * v.y; acc[6][2] += aB.z * v.z; acc[6][3] += aB.z * v.w;
            acc[7][0] += aB.w * v.x; acc[7][1] += aB.w * v.y; acc[7][2] += aB.w * v.z; acc[7][3] += aB.w * v.w;
        }
        __syncthreads();
    }

    // ---- store content: float4, coalesced ----
    #pragma unroll
    for (int ri = 0; ri < 8; ++ri) {
        long row = row0 + rg * 8 + ri;
        float4 o = make_float4(acc[ri][0], acc[ri][1], acc[ri][2], acc[ri][3]);
        *(float4*)&out_content[row * DV + cg * 4] = o;
    }
}

extern "C" void kernel_launch(void* const* d_in, const int* in_sizes, int n_in,
                              void* d_out, int out_size, void* d_ws, size_t ws_size,
                              hipStream_t stream) {
    const float* query  = (const float*)d_in[0];
    const float* W1     = (const float*)d_in[1];
    const float* b1     = (const float*)d_in[2];
    const float* W2     = (const float*)d_in[3];
    const float* b2     = (const float*)d_in[4];
    const float* values = (const float*)d_in[5];
    const float* keys   = (const float*)d_in[6];

    const int nrows = in_sizes[0] / DQ;            // 262144
    float* out_content = (float*)d_out;            // [nrows, 256]
    float* out_attn    = out_content + (size_t)nrows * DV;  // [nrows, 240]

    const int grid = nrows / RB;                   // 8192 blocks
    em_fused<<<grid, 256, 0, stream>>>(query, W1, b1, W2, b2, values, keys,
                                       out_content, out_attn);
}